// Round 1
// baseline (1334.990 us; speedup 1.0000x reference)
//
#include <hip/hip_runtime.h>

#define D_FEAT 32

// Kernel 1: zero the output accumulator and the per-node has-in-edge flags.
__global__ void zero_kernel(float* __restrict__ out, int* __restrict__ flags, int n_nodes) {
    int i = blockIdx.x * blockDim.x + threadIdx.x;
    int total = n_nodes * D_FEAT;
    if (i < total) out[i] = 0.0f;
    if (i < n_nodes) flags[i] = 0;
}

// Kernel 2: per-edge scatter-add. 4 threads per edge, 8 floats per thread.
__global__ void scatter_kernel(const float* __restrict__ hidden,
                               const int* __restrict__ src,
                               const int* __restrict__ dst,
                               float* __restrict__ out,
                               int* __restrict__ flags,
                               int n_edges) {
    int t = blockIdx.x * blockDim.x + threadIdx.x;
    int e = t >> 2;
    int c = t & 3;
    if (e >= n_edges) return;
    int s = src[e];
    int d = dst[e];
    const float4* hp = reinterpret_cast<const float4*>(hidden + (size_t)s * D_FEAT + c * 8);
    float4 a = hp[0];
    float4 b = hp[1];
    float* op = out + (size_t)d * D_FEAT + c * 8;
    unsafeAtomicAdd(op + 0, a.x);
    unsafeAtomicAdd(op + 1, a.y);
    unsafeAtomicAdd(op + 2, a.z);
    unsafeAtomicAdd(op + 3, a.w);
    unsafeAtomicAdd(op + 4, b.x);
    unsafeAtomicAdd(op + 5, b.y);
    unsafeAtomicAdd(op + 6, b.z);
    unsafeAtomicAdd(op + 7, b.w);
    if (c == 0) flags[d] = 1;   // benign race: everyone writes 1
}

// Kernel 3: nodes with no in-edges keep their old hidden value.
__global__ void finalize_kernel(const float* __restrict__ hidden,
                                const int* __restrict__ flags,
                                float* __restrict__ out,
                                int n_nodes) {
    int t = blockIdx.x * blockDim.x + threadIdx.x;
    int n = t >> 2;
    int c = t & 3;
    if (n >= n_nodes) return;
    if (flags[n]) return;
    const float4* hp = reinterpret_cast<const float4*>(hidden + (size_t)n * D_FEAT + c * 8);
    float4* op = reinterpret_cast<float4*>(out + (size_t)n * D_FEAT + c * 8);
    op[0] = hp[0];
    op[1] = hp[1];
}

extern "C" void kernel_launch(void* const* d_in, const int* in_sizes, int n_in,
                              void* d_out, int out_size, void* d_ws, size_t ws_size,
                              hipStream_t stream) {
    const float* hidden = (const float*)d_in[0];
    const int* src = (const int*)d_in[1];
    const int* dst = (const int*)d_in[2];
    float* out = (float*)d_out;
    int n_nodes = in_sizes[0] / D_FEAT;
    int n_edges = in_sizes[1];
    int* flags = (int*)d_ws;

    {
        int total = n_nodes * D_FEAT;
        int blocks = (total + 255) / 256;
        zero_kernel<<<blocks, 256, 0, stream>>>(out, flags, n_nodes);
    }
    {
        long long threads = (long long)n_edges * 4;
        int blocks = (int)((threads + 255) / 256);
        scatter_kernel<<<blocks, 256, 0, stream>>>(hidden, src, dst, out, flags, n_edges);
    }
    {
        long long threads = (long long)n_nodes * 4;
        int blocks = (int)((threads + 255) / 256);
        finalize_kernel<<<blocks, 256, 0, stream>>>(hidden, flags, out, n_nodes);
    }
}

// Round 2
// 303.981 us; speedup vs baseline: 4.3917x; 4.3917x over previous
//
#include <hip/hip_runtime.h>

#define D_FEAT 32

// Kernel 1: zero the per-node cursor array and the global cursor.
__global__ void init_kernel(int* __restrict__ cur, int* __restrict__ cursor, int n_nodes) {
    int i = blockIdx.x * blockDim.x + threadIdx.x;
    if (i < n_nodes) cur[i] = 0;
    if (i == 0) *cursor = 0;
}

// Kernel 2: count in-degree per node.
__global__ void count_kernel(const int* __restrict__ dst, int* __restrict__ cur, int n_edges) {
    int e = blockIdx.x * blockDim.x + threadIdx.x;
    if (e >= n_edges) return;
    atomicAdd(&cur[dst[e]], 1);
}

// Kernel 3: allocate contiguous bucket slices per node.
// Wave-level exclusive scan of counts, one global-cursor atomic per wave.
__global__ void alloc_kernel(int* __restrict__ cur, int* __restrict__ start,
                             int* __restrict__ cursor, int n_nodes) {
    int n = blockIdx.x * blockDim.x + threadIdx.x;
    int lane = threadIdx.x & 63;
    int v = (n < n_nodes) ? cur[n] : 0;
    // inclusive wave scan
    int pre = v;
    for (int off = 1; off < 64; off <<= 1) {
        int t = __shfl_up(pre, off, 64);
        if (lane >= off) pre += t;
    }
    int excl = pre - v;
    int total = __shfl(pre, 63, 64);
    int base = 0;
    if (lane == 0) base = atomicAdd(cursor, total);
    base = __shfl(base, 0, 64);
    if (n < n_nodes) {
        int s = base + excl;
        start[n] = s;
        cur[n] = s;   // running cursor for fill; ends at start+count
    }
}

// Kernel 4: scatter src ids into dst-ordered buckets.
__global__ void fill_kernel(const int* __restrict__ src, const int* __restrict__ dst,
                            int* __restrict__ cur, int* __restrict__ bucket, int n_edges) {
    int e = blockIdx.x * blockDim.x + threadIdx.x;
    if (e >= n_edges) return;
    int d = dst[e];
    int p = atomicAdd(&cur[d], 1);
    bucket[p] = src[e];
}

// Kernel 5: per-node gather-sum. 32 threads per node, thread j owns feature j.
__global__ void gather_kernel(const float* __restrict__ hidden,
                              const int* __restrict__ start, const int* __restrict__ end,
                              const int* __restrict__ bucket,
                              float* __restrict__ out, int n_nodes) {
    int t = blockIdx.x * blockDim.x + threadIdx.x;
    int n = t >> 5;
    int j = t & 31;
    if (n >= n_nodes) return;
    int s0 = start[n];
    int s1 = end[n];   // cur[n] after fill == start + count
    float acc;
    if (s1 == s0) {
        acc = hidden[(size_t)n * D_FEAT + j];   // isolated node keeps old value
    } else {
        acc = 0.0f;
        for (int p = s0; p < s1; ++p) {
            int s = bucket[p];                   // 32 lanes same addr -> broadcast
            acc += hidden[(size_t)s * D_FEAT + j];
        }
    }
    out[(size_t)n * D_FEAT + j] = acc;
}

extern "C" void kernel_launch(void* const* d_in, const int* in_sizes, int n_in,
                              void* d_out, int out_size, void* d_ws, size_t ws_size,
                              hipStream_t stream) {
    const float* hidden = (const float*)d_in[0];
    const int* src = (const int*)d_in[1];
    const int* dst = (const int*)d_in[2];
    float* out = (float*)d_out;
    int n_nodes = in_sizes[0] / D_FEAT;
    int n_edges = in_sizes[1];

    // Workspace layout (ints): [cursor pad 16][start n_nodes][cur n_nodes][bucket n_edges]
    int* cursor = (int*)d_ws;
    int* start  = cursor + 16;
    int* cur    = start + n_nodes;
    int* bucket = cur + n_nodes;

    {
        int blocks = (n_nodes + 255) / 256;
        init_kernel<<<blocks, 256, 0, stream>>>(cur, cursor, n_nodes);
    }
    {
        int blocks = (n_edges + 255) / 256;
        count_kernel<<<blocks, 256, 0, stream>>>(dst, cur, n_edges);
    }
    {
        int blocks = (n_nodes + 255) / 256;
        alloc_kernel<<<blocks, 256, 0, stream>>>(cur, start, cursor, n_nodes);
    }
    {
        int blocks = (n_edges + 255) / 256;
        fill_kernel<<<blocks, 256, 0, stream>>>(src, dst, cur, bucket, n_edges);
    }
    {
        long long threads = (long long)n_nodes * 32;
        int blocks = (int)((threads + 255) / 256);
        gather_kernel<<<blocks, 256, 0, stream>>>(hidden, start, cur, bucket, out, n_nodes);
    }
}